// Round 18
// baseline (36.164 us; speedup 1.0000x reference)
//
#include <hip/hip_runtime.h>

// B=32, H=W=512, C=3, toroidal 3x3 uniform depthwise avg + per-pixel quadratic forms.
// R17 (35.4us: RPW=32, reg-separable conv + LDS store-transpose + dense nt stores)
// + ONE change: prefetch depth 2 -> 4 (rows i+1..i+4 in flight, 20 outstanding
// loads/wave) to cover HBM latency at 4 waves/CU.
#define HH 512
#define ROW4 384            // float4 per image row (512*3/4)
#define RPW 32
#define EPS 0.1f

typedef float vf4 __attribute__((ext_vector_type(4)));

__device__ __forceinline__ void loadF(const float4* __restrict__ rp,
                                      const int* c, float4* F) {
    F[0] = rp[c[0]]; F[1] = rp[c[1]]; F[2] = rp[c[2]];
    F[3] = rp[c[3]]; F[4] = rp[c[4]];
}

__device__ __forceinline__ void hsumF(const float4* F, float* S, float* rawdst) {
    const float g[20] = {F[0].x,F[0].y,F[0].z,F[0].w, F[1].x,F[1].y,F[1].z,F[1].w,
                         F[2].x,F[2].y,F[2].z,F[2].w, F[3].x,F[3].y,F[3].z,F[3].w,
                         F[4].x,F[4].y,F[4].z,F[4].w};
    #pragma unroll
    for (int q = 0; q < 12; ++q) S[q] = g[1+q] + g[4+q] + g[7+q];
    if (rawdst) {
        #pragma unroll
        for (int q = 0; q < 12; ++q) rawdst[q] = g[4+q];
    }
}

__global__ __launch_bounds__(256)
void gnllt_kernel(const float* __restrict__ xin,
                  const float* __restrict__ A,
                  const float* __restrict__ Bm,
                  const float* __restrict__ Cm,
                  const float* __restrict__ bias,
                  const float* __restrict__ wk,
                  float* __restrict__ outp)
{
    __shared__ float4 obuf[4][192];          // 12 KB: wave-private transpose slices

    const int lane  = threadIdx.x & 63;
    const int wsub  = threadIdx.x >> 6;
    const int wid   = (blockIdx.x << 2) | wsub;
    const int strip = wid & 1;
    const int grp   = wid >> 1;              // 0..511
    const int img   = grp >> 4;              // 0..31  (16 row-groups per image)
    const int h0    = (grp & 15) * RPW;      // 0..480

    const float wv = wk[0];
    const float qs = EPS * wv * wv;
    const float qa00 = qs*A[0],  qa11 = qs*A[4],  qa22 = qs*A[8];
    const float qa01 = qs*(A[1]+A[3]),  qa02 = qs*(A[2]+A[6]),  qa12 = qs*(A[5]+A[7]);
    const float qb00 = qs*Bm[0], qb11 = qs*Bm[4], qb22 = qs*Bm[8];
    const float qb01 = qs*(Bm[1]+Bm[3]), qb02 = qs*(Bm[2]+Bm[6]), qb12 = qs*(Bm[5]+Bm[7]);
    const float qc00 = qs*Cm[0], qc11 = qs*Cm[4], qc22 = qs*Cm[8];
    const float qc01 = qs*(Cm[1]+Cm[3]), qc02 = qs*(Cm[2]+Cm[6]), qc12 = qs*(Cm[5]+Cm[7]);
    const float bi0 = EPS*bias[0], bi1 = EPS*bias[1], bi2 = EPS*bias[2];

    const float4* x4 = (const float4*)xin;
    float4*       ob = obuf[wsub];

    const int cb = strip * 192 + 3 * lane;
    int c[5];
    #pragma unroll
    for (int j = 0; j < 5; ++j) {
        int v = cb - 1 + j;
        if (v < 0)     v += ROW4;
        if (v >= ROW4) v -= ROW4;
        c[j] = v;
    }
    const size_t ib = (size_t)img * (HH * ROW4);

    auto rowp = [&](int r) {
        return x4 + ib + (size_t)((h0 + r + HH) & (HH - 1)) * ROW4;
    };

    float hs[3][12];     // hsum slot(r) = (r+1)%3
    float raw[2][12];    // raw(r) in raw[r&1]
    float4 Fb[4][5];     // F(r) in Fb[r&3], 4-deep rolling prefetch
    float4 T0[5], T1[5];

    // Prime: rows -1, 0 immediate; rows 1..3 prefetched into their slots.
    loadF(rowp(-1), c, T0);
    loadF(rowp(0),  c, T1);
    loadF(rowp(1),  c, Fb[1]);
    loadF(rowp(2),  c, Fb[2]);
    loadF(rowp(3),  c, Fb[3]);
    hsumF(T0, hs[0], nullptr);
    hsumF(T1, hs[1], raw[0]);

    #pragma unroll
    for (int i = 0; i < RPW; ++i) {
        // 1) Prefetch row i+4 (4-deep) into the slot freed last iteration.
        if (i < RPW - 3) loadF(rowp(i + 4), c, Fb[i & 3]);

        // 2) Consume F(i+1), issued 3 iterations ago.
        hsumF(Fb[(i + 1) & 3], hs[(i + 2) % 3], raw[(i + 1) & 1]);

        const float* hm = hs[i % 3];
        const float* hc = hs[(i + 1) % 3];
        const float* hp = hs[(i + 2) % 3];
        const float* rw = raw[i & 1];

        float of[12];
        #pragma unroll
        for (int j = 0; j < 4; ++j) {
            const float s0 = hm[3*j+0] + hc[3*j+0] + hp[3*j+0];
            const float s1 = hm[3*j+1] + hc[3*j+1] + hp[3*j+1];
            const float s2 = hm[3*j+2] + hc[3*j+2] + hp[3*j+2];
            const float p00 = s0*s0, p11 = s1*s1, p22 = s2*s2;
            const float p01 = s0*s1, p02 = s0*s2, p12 = s1*s2;
            of[3*j+0] = rw[3*j+0] + bi0 + qa00*p00 + qa11*p11 + qa22*p22
                                        + qa01*p01 + qa02*p02 + qa12*p12;
            of[3*j+1] = rw[3*j+1] + bi1 + qb00*p00 + qb11*p11 + qb22*p22
                                        + qb01*p01 + qb02*p02 + qb12*p12;
            of[3*j+2] = rw[3*j+2] + bi2 + qc00*p00 + qc11*p11 + qc22*p22
                                        + qc01*p01 + qc02*p02 + qc12*p12;
        }

        // Wave-private LDS transpose (conflict-free), in-wave fence, then
        // 3 dense 1KB non-temporal store instructions.
        ob[3*lane + 0] = make_float4(of[0], of[1], of[2],  of[3]);
        ob[3*lane + 1] = make_float4(of[4], of[5], of[6],  of[7]);
        ob[3*lane + 2] = make_float4(of[8], of[9], of[10], of[11]);
        asm volatile("s_waitcnt lgkmcnt(0)" ::: "memory");
        const float4 s0 = ob[lane], s1 = ob[lane + 64], s2 = ob[lane + 128];

        vf4* op = (vf4*)(outp + 4 * (ib + (size_t)(h0 + i) * ROW4 + strip * 192));
        vf4 v0 = {s0.x, s0.y, s0.z, s0.w};
        vf4 v1 = {s1.x, s1.y, s1.z, s1.w};
        vf4 v2 = {s2.x, s2.y, s2.z, s2.w};
        __builtin_nontemporal_store(v0, op + lane);
        __builtin_nontemporal_store(v1, op + lane + 64);
        __builtin_nontemporal_store(v2, op + lane + 128);
    }
}

extern "C" void kernel_launch(void* const* d_in, const int* in_sizes, int n_in,
                              void* d_out, int out_size, void* d_ws, size_t ws_size,
                              hipStream_t stream) {
    const float* x    = (const float*)d_in[0];
    const float* A    = (const float*)d_in[1];
    const float* Bm   = (const float*)d_in[2];
    const float* Cm   = (const float*)d_in[3];
    const float* bias = (const float*)d_in[4];
    const float* wk   = (const float*)d_in[5];
    float* out = (float*)d_out;

    // 32 imgs x 16 row-groups x 2 strips = 1024 waves = 256 blocks (1 per CU)
    dim3 grid(256);
    dim3 block(256);
    gnllt_kernel<<<grid, block, 0, stream>>>(x, A, Bm, Cm, bias, wk, out);
}